// Round 2
// baseline (63.363 us; speedup 1.0000x reference)
//
#include <hip/hip_runtime.h>

#define HH 128
#define WW 128
#define CC 64
#define KDIM 16
#define HW (HH * WW)
#define TOTBYTES (4u * CC * HW * 4u)   // B=4 batches * C * H * W * sizeof(float)

using int32x4_t = __attribute__((ext_vector_type(4))) int;

// CK-style raw buffer load: OOB (voffset+soffset+4 > num_records) returns 0.
__device__ float llvm_amdgcn_raw_buffer_load_fp32(int32x4_t srsrc, int voffset,
                                                  int soffset, int glc_slc)
    __asm("llvm.amdgcn.raw.buffer.load.f32");

__device__ inline int32x4_t make_srd(const void* p, unsigned bytes) {
    const unsigned long long a = (unsigned long long)p;
    int32x4_t r;
    r.x = (int)(a & 0xffffffffull);
    r.y = (int)(a >> 32);          // stride bits zero
    r.z = (int)bytes;              // num_records (bytes, stride==0)
    r.w = 0x00020000;              // raw untyped dword access
    return r;
}

#if __has_builtin(__builtin_amdgcn_exp2f)
#define FAST_EXP2(x) __builtin_amdgcn_exp2f(x)
#define KLOG2E 1.44269504088896340736f
#else
#define FAST_EXP2(x) __expf(x)     // fallback: arg is q*k un-scaled
#define KLOG2E 1.0f
#endif

#define OOB_SENT 0x40000000        // 1 GB: always OOB (tensor = 16 MB), no 32-bit wrap

// Block: 256 threads = 4 waves; lane = pixel in a 16(w) x 4(h) tile.
// Phase 1: wave g computes k[d] for d in [4g,4g+4) over its 64 pixels.
// Phase 2: wave g handles channels c in [16g,16g+16).
__global__ __launch_bounds__(256, 4) void gatev_fused(
    const float* __restrict__ x, const float* __restrict__ y,
    const float* __restrict__ z,
    const float* __restrict__ Wq, const float* __restrict__ bq,
    const float* __restrict__ Wk, const float* __restrict__ bk,
    const float* __restrict__ wv, const float* __restrict__ bv,
    float* __restrict__ out)
{
    __shared__ float k_lds[64][16];

    const int tid  = threadIdx.x;
    const int g    = tid >> 6;
    const int lane = tid & 63;
    const int px   = lane & 15, py = lane >> 4;
    const int b    = blockIdx.z;
    const int h    = blockIdx.y * 4 + py;
    const int w    = blockIdx.x * 16 + px;
    const int pix  = h * WW + w;

    const int32x4_t rx = make_srd(x, TOTBYTES);
    const int32x4_t ry = make_srd(y, TOTBYTES);
    const int32x4_t rz = make_srd(z, TOTBYTES);

    // 9 tap byte-offsets within one channel plane; OOB taps -> sentinel -> load 0
    int boff[9];
#pragma unroll
    for (int t = 0; t < 9; ++t) {
        const int dy = t / 3 - 1, dx = t % 3 - 1;
        const int hh = h + dy, ww = w + dx;
        const bool ok = (hh >= 0) & (hh < HH) & (ww >= 0) & (ww < WW);
        boff[t] = ok ? (hh * WW + ww) * 4 : OOB_SENT;
    }

    const int base = b * CC * HW * 4;     // batch byte offset (uniform)

    // ---------------- phase 1: k = relu(conv3x3(x) + bk), 4 d's per wave ----
    const int d0  = g * 4;
    const int wb0 = __builtin_amdgcn_readfirstlane(d0 * CC * 9);

    float acc0 = 0.f, acc1 = 0.f, acc2 = 0.f, acc3 = 0.f;
    float xv0[9], xv1[9];
    int sof = base;
#pragma unroll
    for (int t = 0; t < 9; ++t)
        xv0[t] = llvm_amdgcn_raw_buffer_load_fp32(rx, boff[t], sof, 0);

    for (int c = 0; c < CC; c += 2) {
        const float* wp = Wk + wb0 + c * 9;
        // prefetch c+1 while computing c
#pragma unroll
        for (int t = 0; t < 9; ++t)
            xv1[t] = llvm_amdgcn_raw_buffer_load_fp32(rx, boff[t], sof + HW * 4, 0);
#pragma unroll
        for (int t = 0; t < 9; ++t) {
            acc0 = fmaf(wp[t],        xv0[t], acc0);
            acc1 = fmaf(wp[576 + t],  xv0[t], acc1);
            acc2 = fmaf(wp[1152 + t], xv0[t], acc2);
            acc3 = fmaf(wp[1728 + t], xv0[t], acc3);
        }
        // prefetch c+2 (last one reads past batch: OOB-zero or discarded) while computing c+1
#pragma unroll
        for (int t = 0; t < 9; ++t)
            xv0[t] = llvm_amdgcn_raw_buffer_load_fp32(rx, boff[t], sof + 2 * HW * 4, 0);
        const float* wp1 = wp + 9;
#pragma unroll
        for (int t = 0; t < 9; ++t) {
            acc0 = fmaf(wp1[t],        xv1[t], acc0);
            acc1 = fmaf(wp1[576 + t],  xv1[t], acc1);
            acc2 = fmaf(wp1[1152 + t], xv1[t], acc2);
            acc3 = fmaf(wp1[1728 + t], xv1[t], acc3);
        }
        sof += 2 * HW * 4;
    }
    {
        const float4 bb = *(const float4*)&bk[d0];
        float4 kk;   // pre-scale by log2e so exp arg is a single mul
        kk.x = fmaxf(acc0 + bb.x, 0.f) * KLOG2E;
        kk.y = fmaxf(acc1 + bb.y, 0.f) * KLOG2E;
        kk.z = fmaxf(acc2 + bb.z, 0.f) * KLOG2E;
        kk.w = fmaxf(acc3 + bb.w, 0.f) * KLOG2E;
        *(float4*)&k_lds[lane][d0] = kk;
    }
    __syncthreads();

    // ---------------- phase 2: q, v, softmax-attention, 16 c's per wave -----
    float kl[16];
#pragma unroll
    for (int t = 0; t < 4; ++t) {
        const float4 kk = *(const float4*)&k_lds[lane][t * 4];
        kl[4 * t + 0] = kk.x; kl[4 * t + 1] = kk.y;
        kl[4 * t + 2] = kk.z; kl[4 * t + 3] = kk.w;
    }
    float wvr[16], bvr[16];
#pragma unroll
    for (int d = 0; d < KDIM; ++d) { wvr[d] = wv[d]; bvr[d] = bv[d]; }

    const int c0u  = __builtin_amdgcn_readfirstlane(g * 16);
    const int pixb = pix * 4;
    float* ob = out + (size_t)(b * CC) * HW;

    auto attn_step = [&](int c, const float (&yv)[9], float zv) {
        const float* wq = Wq + c * 9;
        float q = 0.f;
#pragma unroll
        for (int t = 0; t < 9; ++t) q = fmaf(wq[t], yv[t], q);
        q = fmaxf(q + bq[c], 0.f);

        float num = 0.f, den = 0.f;
#pragma unroll
        for (int d = 0; d < KDIM; ++d) {
            const float e = FAST_EXP2(q * kl[d]);
            const float v = fmaxf(fmaf(zv, wvr[d], bvr[d]), 0.f);
            num = fmaf(e, v, num);
            den += e;
        }
        ob[c * HW + pix] = __fdividef(num, den);
    };

    float yv0[9], yv1[9], zv0, zv1;
    int sof2 = base + c0u * HW * 4;
#pragma unroll
    for (int t = 0; t < 9; ++t)
        yv0[t] = llvm_amdgcn_raw_buffer_load_fp32(ry, boff[t], sof2, 0);
    zv0 = llvm_amdgcn_raw_buffer_load_fp32(rz, pixb, sof2, 0);

    for (int ci = 0; ci < 16; ci += 2) {
        // prefetch ci+1
#pragma unroll
        for (int t = 0; t < 9; ++t)
            yv1[t] = llvm_amdgcn_raw_buffer_load_fp32(ry, boff[t], sof2 + HW * 4, 0);
        zv1 = llvm_amdgcn_raw_buffer_load_fp32(rz, pixb, sof2 + HW * 4, 0);

        attn_step(c0u + ci, yv0, zv0);

        // prefetch ci+2 (last reads past range: OOB-zero or next batch, discarded)
#pragma unroll
        for (int t = 0; t < 9; ++t)
            yv0[t] = llvm_amdgcn_raw_buffer_load_fp32(ry, boff[t], sof2 + 2 * HW * 4, 0);
        zv0 = llvm_amdgcn_raw_buffer_load_fp32(rz, pixb, sof2 + 2 * HW * 4, 0);

        attn_step(c0u + ci + 1, yv1, zv1);

        sof2 += 2 * HW * 4;
    }
}

extern "C" void kernel_launch(void* const* d_in, const int* in_sizes, int n_in,
                              void* d_out, int out_size, void* d_ws, size_t ws_size,
                              hipStream_t stream) {
    const float* x  = (const float*)d_in[0];
    const float* y  = (const float*)d_in[1];
    const float* z  = (const float*)d_in[2];
    const float* Wq = (const float*)d_in[3];
    const float* bq = (const float*)d_in[4];
    const float* Wk = (const float*)d_in[5];
    const float* bk = (const float*)d_in[6];
    const float* wv = (const float*)d_in[7];
    const float* bv = (const float*)d_in[8];
    float* out = (float*)d_out;

    dim3 grid(WW / 16, HH / 4, 4);   // (8, 32, 4) = 1024 blocks
    dim3 block(256);
    hipLaunchKernelGGL(gatev_fused, grid, block, 0, stream,
                       x, y, z, Wq, bq, Wk, bk, wv, bv, out);
}